// Round 4
// baseline (247.272 us; speedup 1.0000x reference)
//
#include <hip/hip_runtime.h>
#include <hip/hip_bf16.h>
#include <math.h>

namespace {

constexpr int Kn   = 32;
constexpr int CIN  = 64;
constexpr int COUT = 64;
constexpr int Mn   = 8;
constexpr int HIDn = 16;
constexpr int NK   = 65536;         // N*K
constexpr int PTOT = 262144;        // B*N*K
constexpr float EPSf = 1e-5f;

constexpr int NBLK = 256;           // == #CUs: 1 block/CU, all resident
constexpr int NTHR = 1024;          // 16 waves

// ws float-offset layout
constexpr int WS_SUM1 = 0;    // 16 floats
constexpr int WS_SQ1  = 16;   // 16
constexpr int WS_SUM2 = 64;   // 64
constexpr int WS_SQ2  = 128;  // 64
constexpr int WS_BAR  = 192;  // int barrier counter (monotone)
constexpr int WS_TOT  = 256;

typedef short bf16x8 __attribute__((ext_vector_type(8)));
typedef float f32x4  __attribute__((ext_vector_type(4)));

__device__ __forceinline__ short f2bf(float f) {
  union { __hip_bfloat16 h; unsigned short u; } cv;
  cv.h = __float2bfloat16(f);
  return (short)cv.u;
}

// device-scope load (bypass possibly-stale L1 after grid barrier)
__device__ __forceinline__ float ws_ld(const float* p) {
  return __hip_atomic_load(p, __ATOMIC_RELAXED, __HIP_MEMORY_SCOPE_AGENT);
}

// Manual grid barrier: monotone counter, target = k*NBLK for the k-th barrier.
// __syncthreads() drains vmcnt(0) first, so prior global atomics are complete
// before the arrive-increment.
__device__ __forceinline__ void gridbar(int* cnt, int tid, int target) {
  __syncthreads();
  if (tid == 0) {
    __hip_atomic_fetch_add(cnt, 1, __ATOMIC_ACQ_REL, __HIP_MEMORY_SCOPE_AGENT);
    while (__hip_atomic_load(cnt, __ATOMIC_ACQUIRE,
                             __HIP_MEMORY_SCOPE_AGENT) < target) {
      __builtin_amdgcn_s_sleep(8);
    }
  }
  __syncthreads();
}

// Build 14-ch geometric feature and h = w1 @ x (16 channels) for one position.
__device__ __forceinline__ void geom_h(
    const float* __restrict__ xyz, const float* __restrict__ dist,
    const float* __restrict__ nrm, const float* __restrict__ ang,
    const float* __restrict__ w1, int b, int rem, float h[HIDn]) {
  const int cbase = rem & ~(Kn - 1);   // k = 0 element of this (b, n)
  float x[14];
  const float invd = 1.0f / (1.0f + dist[b * NK + rem]);
  float xe = 0.f, ne = 0.f;
#pragma unroll
  for (int d = 0; d < 3; ++d) {
    const int base = (b * 3 + d) * NK;
    const float gx = xyz[base + rem];
    const float gn = nrm[base + rem];
    const float cn = nrm[base + cbase];
    const float ga = ang[base + rem];
    const float nd = gn - cn;
    x[d] = gx; x[4 + d] = gn; x[7 + d] = nd; x[11 + d] = ga;
    xe += gx * gx; ne += nd * nd;
  }
  x[3]  = sqrtf(xe);
  x[10] = sqrtf(ne);
#pragma unroll
  for (int i = 0; i < 14; ++i) x[i] *= invd;
#pragma unroll
  for (int o = 0; o < HIDn; ++o) {
    float s = 0.f;
#pragma unroll
    for (int c = 0; c < 14; ++c) s = fmaf(w1[o * 14 + c], x[c], s);
    h[o] = s;
  }
}

__global__ __launch_bounds__(512) void k0_zero(float* __restrict__ ws) {
  if (threadIdx.x < WS_TOT) ws[threadIdx.x] = 0.f;
}

// One persistent kernel: BN1 stats -> gridbar -> scores + MFMA GEMM (acc in
// registers) + BN2 stats -> gridbar -> BN2+ReLU epilogue.
__global__ __launch_bounds__(NTHR, 4) void kmain(
    const float* __restrict__ xyz, const float* __restrict__ dist,
    const float* __restrict__ nrm, const float* __restrict__ ang,
    const float* __restrict__ feature, const float* __restrict__ w1,
    const float* __restrict__ g1, const float* __restrict__ b1,
    const float* __restrict__ w2, const float* __restrict__ bias2,
    const float* __restrict__ wb, const float* __restrict__ gamma,
    const float* __restrict__ beta, float* __restrict__ ws,
    float* __restrict__ out) {
  __shared__ short lds_b[16 * 4 * 64 * 8];   // 64 KB Wb fragments (bf16)
  __shared__ float red[16][128];             // 8 KB reductions
  __shared__ float bnp[160];  // [0:16] sc1 [16:32] sh1 [32:96] sc2 [96:160] sh2

  int* const bar = (int*)(ws + WS_BAR);

  const int tid = threadIdx.x;
  const int l   = tid & 63;
  const int w   = tid >> 6;          // wave 0..15
  const int g   = l >> 4;            // k-lane-group 0..3
  const int row = l & 15;

  const int blk = blockIdx.x;
  const int pos = blk * NTHR + tid;  // this thread's position (phases A & C)
  const int b   = pos >> 16;         // uniform per block (1024 | NK)
  const int rem = pos & (NK - 1);

  // ---- stage Wb into LDS as fragment-major bf16 (round-2-validated) ----
#pragma unroll
  for (int ff = 0; ff < 4; ++ff) {
    const int fi   = w * 4 + ff;
    const int t    = fi >> 2;
    const int colt = fi & 3;
    const int c    = t * 4 + g;
    const int o    = colt * 16 + row;
    bf16x8 frag;
#pragma unroll
    for (int j = 0; j < 8; ++j) frag[j] = f2bf(wb[c * 512 + j * 64 + o]);
    *reinterpret_cast<bf16x8*>(&lds_b[(fi * 64 + l) * 8]) = frag;
  }

  // ---- phase A: geom + h (kept in regs), BN1 sums ----
  float h[HIDn];
  geom_h(xyz, dist, nrm, ang, w1, b, rem, h);
  {
    float v[32];
#pragma unroll
    for (int i = 0; i < 16; ++i) { v[i] = h[i]; v[16 + i] = h[i] * h[i]; }
#pragma unroll
    for (int off = 32; off >= 1; off >>= 1) {
#pragma unroll
      for (int i = 0; i < 32; ++i) v[i] += __shfl_xor(v[i], off);
    }
    float mv = 0.f;
#pragma unroll
    for (int i = 0; i < 32; ++i) { if (l == i) mv = v[i]; }
    if (l < 32) red[w][l] = mv;
    __syncthreads();
    if (tid < 32) {
      float tot = 0.f;
#pragma unroll
      for (int ww = 0; ww < 16; ++ww) tot += red[ww][tid];
      atomicAdd(&ws[WS_SUM1 + tid], tot);   // [0:16]=sum, [16:32]=sumsq
    }
  }

  gridbar(bar, tid, NBLK);   // ---- grid barrier #1 ----

  // ---- phase B: every block finalizes BN1 (redundant, no extra sync) ----
  if (tid < HIDn) {
    const float inv  = 1.0f / (float)PTOT;
    const float mean = ws_ld(&ws[WS_SUM1 + tid]) * inv;
    const float var  = ws_ld(&ws[WS_SQ1 + tid]) * inv - mean * mean;
    const float s    = g1[tid] * rsqrtf(var + EPSf);
    bnp[tid]      = s;
    bnp[16 + tid] = b1[tid] - mean * s;
  }
  __syncthreads();

  // ---- phase C: scorenet from cached h ----
  float sc[Mn];
  {
#pragma unroll
    for (int o = 0; o < HIDn; ++o)
      h[o] = fmaxf(fmaf(h[o], bnp[o], bnp[16 + o]), 0.f);
    float s[Mn];
#pragma unroll
    for (int m = 0; m < Mn; ++m) {
      float a = bias2[m];
#pragma unroll
      for (int j = 0; j < HIDn; ++j) a = fmaf(w2[m * HIDn + j], h[j], a);
      s[m] = a;
    }
    float mx = s[0];
#pragma unroll
    for (int m = 1; m < Mn; ++m) mx = fmaxf(mx, s[m]);
    float ssum = 0.f;
#pragma unroll
    for (int m = 0; m < Mn; ++m) { sc[m] = expf(s[m] - mx); ssum += sc[m]; }
    const float inv = 1.0f / (ssum + expf(-mx));   // softmax_one
#pragma unroll
    for (int m = 0; m < Mn; ++m) sc[m] *= inv;
  }

  // ---- GEMM: wave owns 64 positions = 4 row-tiles, 2 pairs ----
  const int wrem = (blk * NTHR + w * 64) & (NK - 1);
  const float* fbase = feature + (size_t)b * CIN * NK + wrem;
  f32x4 acc[4][4];
#pragma unroll
  for (int r = 0; r < 4; ++r)
#pragma unroll
    for (int j = 0; j < 4; ++j) acc[r][j] = (f32x4){0.f, 0.f, 0.f, 0.f};

#pragma unroll
  for (int pr = 0; pr < 2; ++pr) {
    float s0[Mn], s1[Mn];
#pragma unroll
    for (int m = 0; m < Mn; ++m) {
      s0[m] = __shfl(sc[m], pr * 32 + row);
      s1[m] = __shfl(sc[m], pr * 32 + 16 + row);
    }
#pragma unroll
    for (int t = 0; t < 16; ++t) {
      const int c = t * 4 + g;
      const float fA = fbase[c * NK + pr * 32 + row];
      const float fB = fbase[c * NK + pr * 32 + 16 + row];
      bf16x8 a0, a1;
#pragma unroll
      for (int m = 0; m < Mn; ++m) {
        a0[m] = f2bf(fA * s0[m]);
        a1[m] = f2bf(fB * s1[m]);
      }
#pragma unroll
      for (int ct = 0; ct < 4; ++ct) {
        const bf16x8 bfr = *reinterpret_cast<const bf16x8*>(
            &lds_b[((t * 4 + ct) * 64 + l) * 8]);
        acc[pr * 2 + 0][ct] = __builtin_amdgcn_mfma_f32_16x16x32_bf16(
            a0, bfr, acc[pr * 2 + 0][ct], 0, 0, 0);
        acc[pr * 2 + 1][ct] = __builtin_amdgcn_mfma_f32_16x16x32_bf16(
            a1, bfr, acc[pr * 2 + 1][ct], 0, 0, 0);
      }
    }
  }

  // ---- BN2 partial sums from register accumulators ----
  {
    float s2[4], q2[4];
#pragma unroll
    for (int ct = 0; ct < 4; ++ct) {
      float a = 0.f, q = 0.f;
#pragma unroll
      for (int r = 0; r < 4; ++r)
#pragma unroll
        for (int i = 0; i < 4; ++i) {
          const float vv = acc[r][ct][i];
          a += vv; q += vv * vv;
        }
      s2[ct] = a; q2[ct] = q;
    }
#pragma unroll
    for (int ct = 0; ct < 4; ++ct) {
      s2[ct] += __shfl_xor(s2[ct], 16); s2[ct] += __shfl_xor(s2[ct], 32);
      q2[ct] += __shfl_xor(q2[ct], 16); q2[ct] += __shfl_xor(q2[ct], 32);
    }
    if (l < 16) {
#pragma unroll
      for (int ct = 0; ct < 4; ++ct) {
        red[w][ct * 16 + l]      = s2[ct];
        red[w][64 + ct * 16 + l] = q2[ct];
      }
    }
    __syncthreads();
    if (tid < 128) {
      float tot = 0.f;
#pragma unroll
      for (int ww = 0; ww < 16; ++ww) tot += red[ww][tid];
      atomicAdd(&ws[WS_SUM2 + tid], tot);   // [64:128]=sum2, [128:192]=sq2
    }
  }

  gridbar(bar, tid, 2 * NBLK);   // ---- grid barrier #2 ----

  // ---- phase D: every block finalizes BN2 ----
  if (tid < COUT) {
    const float inv  = 1.0f / (float)PTOT;
    const float mean = ws_ld(&ws[WS_SUM2 + tid]) * inv;
    const float var  = ws_ld(&ws[WS_SQ2 + tid]) * inv - mean * mean;
    const float s    = gamma[tid] * rsqrtf(var + EPSf);
    bnp[32 + tid] = s;
    bnp[96 + tid] = beta[tid] - mean * s;
  }
  __syncthreads();

  // ---- phase E: BN2 + ReLU on register acc, single global write ----
  // D mapping (m89): o = ct*16 + (lane&15); regs i = 4 consecutive positions
  // at offset r*16 + 4*g.
  float* obase = out + (size_t)b * COUT * NK + wrem;
#pragma unroll
  for (int r = 0; r < 4; ++r) {
#pragma unroll
    for (int ct = 0; ct < 4; ++ct) {
      const int o = ct * 16 + row;
      const float scl = bnp[32 + o];
      const float sh  = bnp[96 + o];
      f32x4 vv = acc[r][ct];
#pragma unroll
      for (int i = 0; i < 4; ++i) vv[i] = fmaxf(fmaf(vv[i], scl, sh), 0.f);
      *reinterpret_cast<f32x4*>(&obase[(size_t)o * NK + r * 16 + 4 * g]) = vv;
    }
  }
}

}  // namespace

extern "C" void kernel_launch(void* const* d_in, const int* in_sizes, int n_in,
                              void* d_out, int out_size, void* d_ws, size_t ws_size,
                              hipStream_t stream) {
  const float* xyz     = (const float*)d_in[0];
  const float* dist    = (const float*)d_in[1];
  const float* nrm     = (const float*)d_in[2];
  const float* ang     = (const float*)d_in[3];
  const float* feature = (const float*)d_in[4];
  const float* w1      = (const float*)d_in[5];
  const float* g1      = (const float*)d_in[6];
  const float* b1      = (const float*)d_in[7];
  const float* w2      = (const float*)d_in[8];
  const float* bias2   = (const float*)d_in[9];
  const float* wb      = (const float*)d_in[10];
  const float* gamma   = (const float*)d_in[11];
  const float* beta    = (const float*)d_in[12];
  float* out = (float*)d_out;
  float* ws  = (float*)d_ws;

  hipLaunchKernelGGL(k0_zero, dim3(1), dim3(512), 0, stream, ws);
  hipLaunchKernelGGL(kmain, dim3(NBLK), dim3(NTHR), 0, stream,
                     xyz, dist, nrm, ang, feature, w1, g1, b1,
                     w2, bias2, wb, gamma, beta, ws, out);
}